// Round 1
// baseline (348.434 us; speedup 1.0000x reference)
//
#include <hip/hip_runtime.h>
#include <cstdint>

typedef _Float16 f16;
typedef __attribute__((ext_vector_type(8))) _Float16 f16x8;
typedef __attribute__((ext_vector_type(4))) float f32x4;

#define NB 2
#define NH 46
#define NW 96
#define NHW 4416
#define ND 256
#define NTILES 276   // NHW / 16
#define SSTR 4424    // 4416 + 8 pad (keeps b128 frag alignment irrelevant; breaks write-bank aliasing)

// ---- workspace byte offsets (total 9,312,512 B needed) ----
#define OFF_WFQ 0          // (Wf@Wq)/16  f16 [256][256]
#define OFF_WFK 131072     // Wf@Wk       f16 [256][256]
#define OFF_PQ  262144     // (Wpos@Wq)/16 f32 [2][256]
#define OFF_PK  264192     // Wpos@Wk      f32 [2][256]
#define OFF_BQ  266240     // (bf@Wq)/16   f32 [256]
#define OFF_BK  267264     // bf@Wk        f32 [256]
#define OFF_GS  268288     // (Wpos@Wposᵀ)/16 f32 [2][2]
#define OFF_Q   268544     // q/16 f16 [8832][256]
#define OFF_K   4790528    // k    f16 [8832][256]

// ============ K0: tiny weight-product precompute ============
__global__ __launch_bounds__(256) void prep_kernel(
    const float* __restrict__ Wf, const float* __restrict__ bf,
    const float* __restrict__ Wpos, const float* __restrict__ Wq,
    const float* __restrict__ Wk, char* __restrict__ ws) {
  f16* WFQ = (f16*)(ws + OFF_WFQ);
  f16* WFK = (f16*)(ws + OFF_WFK);
  float* PQ = (float*)(ws + OFF_PQ);
  float* PK = (float*)(ws + OFF_PK);
  float* BQ = (float*)(ws + OFF_BQ);
  float* BK = (float*)(ws + OFF_BK);
  float* GS = (float*)(ws + OFF_GS);
  int bid = blockIdx.x, d = threadIdx.x;
  if (bid < 256) {           // row c of Wf@Wq and Wf@Wk
    int c = bid;
    float aq = 0.f, ak = 0.f;
    for (int t = 0; t < 256; ++t) {
      float wf = Wf[c * 256 + t];
      aq += wf * Wq[t * 256 + d];
      ak += wf * Wk[t * 256 + d];
    }
    WFQ[c * 256 + d] = (f16)(aq * 0.0625f);
    WFK[c * 256 + d] = (f16)ak;
  } else if (bid == 256) {   // Wpos@Wq, Wpos@Wk, bf@Wq, bf@Wk
    float pq0 = 0, pq1 = 0, pk0 = 0, pk1 = 0, bq = 0, bk = 0;
    for (int c = 0; c < 256; ++c) {
      float wq = Wq[c * 256 + d], wk = Wk[c * 256 + d];
      pq0 += Wpos[c] * wq;       pq1 += Wpos[256 + c] * wq;
      pk0 += Wpos[c] * wk;       pk1 += Wpos[256 + c] * wk;
      bq  += bf[c] * wq;         bk  += bf[c] * wk;
    }
    PQ[d] = pq0 * 0.0625f; PQ[256 + d] = pq1 * 0.0625f;
    PK[d] = pk0;           PK[256 + d] = pk1;
    BQ[d] = bq * 0.0625f;  BK[d] = bk;
  } else if (d < 4) {        // G = Wpos@Wposᵀ / 16
    int a = d >> 1, b2 = d & 1;
    float g = 0;
    for (int t = 0; t < 256; ++t) g += Wpos[a * 256 + t] * Wpos[b2 * 256 + t];
    GS[d] = g * 0.0625f;
  }
}

// ============ K1: q_s/k = fmapᵀ @ Wfx + rank-2 pos + bias (fused transpose) ============
// grid (138, 4, 2): x = 64-row tile, y = 64-col tile, z = 0:q 1:k. 256 thr = 4 waves.
__global__ __launch_bounds__(256) void qk_gemm(
    const float* __restrict__ fmap1, const float* __restrict__ fmap2,
    const float* __restrict__ coords1, char* __restrict__ ws) {
  __shared__ f16 As[64 * 40];   // A[row][k], stride 40 (16B-aligned b128 reads)
  __shared__ f16 Bs[64 * 40];   // Wᵀ tile: Bs[d][k]
  __shared__ float py[64], px[64];
  const int z = blockIdx.z;
  const float* fmap = z ? fmap2 : fmap1;
  const f16* Wt = (const f16*)(ws + (z ? OFF_WFK : OFF_WFQ));
  const float* P = (const float*)(ws + (z ? OFF_PK : OFF_PQ));
  const float* bias = (const float*)(ws + (z ? OFF_BK : OFF_BQ));
  f16* outb = (f16*)(ws + (z ? OFF_K : OFF_Q));
  const int t = threadIdx.x;
  const int g0 = blockIdx.x * 64;
  const int b = g0 / NHW;
  const int hwb = g0 - b * NHW;      // 4416 % 64 == 0, block never crosses batch
  const int d0 = blockIdx.y * 64;
  if (t < 64) {
    int hw = hwb + t;
    if (z == 0) {                    // queries: per-row (y,x) from coords1 (ch0=x, ch1=y)
      py[t] = coords1[(b * 2 + 1) * NHW + hw];
      px[t] = coords1[(b * 2 + 0) * NHW + hw];
    } else {                         // keys: grid coords
      int y = hw / NW;
      py[t] = (float)y;
      px[t] = (float)(hw - y * NW);
    }
  }
  const int lane = t & 63, wave = t >> 6;
  const int wr = (wave >> 1) * 32, wc = (wave & 1) * 32;
  const int hwl = t & 63, cl0 = t >> 6;
  f32x4 acc[2][2] = {};
  for (int kt = 0; kt < 8; ++kt) {
    int kk = kt * 32;
    __syncthreads();
#pragma unroll
    for (int i = 0; i < 8; ++i) {
      int c = cl0 + i * 4;
      As[hwl * 40 + c] = (f16)fmap[(size_t)(b * ND + kk + c) * NHW + hwb + hwl];
      Bs[hwl * 40 + c] = Wt[(kk + c) * ND + d0 + hwl];   // hwl = d here
    }
    __syncthreads();
    int row = lane & 15, kq = (lane >> 4) * 8;
    f16x8 a0 = *(const f16x8*)&As[(wr + row) * 40 + kq];
    f16x8 a1 = *(const f16x8*)&As[(wr + 16 + row) * 40 + kq];
    f16x8 b0 = *(const f16x8*)&Bs[(wc + row) * 40 + kq];
    f16x8 b1 = *(const f16x8*)&Bs[(wc + 16 + row) * 40 + kq];
    acc[0][0] = __builtin_amdgcn_mfma_f32_16x16x32_f16(a0, b0, acc[0][0], 0, 0, 0);
    acc[0][1] = __builtin_amdgcn_mfma_f32_16x16x32_f16(a0, b1, acc[0][1], 0, 0, 0);
    acc[1][0] = __builtin_amdgcn_mfma_f32_16x16x32_f16(a1, b0, acc[1][0], 0, 0, 0);
    acc[1][1] = __builtin_amdgcn_mfma_f32_16x16x32_f16(a1, b1, acc[1][1], 0, 0, 0);
  }
#pragma unroll
  for (int fi = 0; fi < 2; ++fi)
#pragma unroll
    for (int fj = 0; fj < 2; ++fj)
#pragma unroll
      for (int r = 0; r < 4; ++r) {
        int rowl = wr + fi * 16 + (lane >> 4) * 4 + r;
        int d = d0 + wc + fj * 16 + (lane & 15);
        float v = acc[fi][fj][r] + bias[d] + py[rowl] * P[d] + px[rowl] * P[ND + d];
        outb[(size_t)(g0 + rowl) * ND + d] = (f16)v;
      }
}

// ============ K2: fused scores-GEMM + softmax + pyramid + 4-level lookup ============
// 552 blocks (16 query rows each), 512 threads (8 waves). ~147 KB LDS, 1 block/CU.
__global__ __launch_bounds__(512) void attn_lookup(
    const float* __restrict__ coords1, const float* __restrict__ clup,
    const char* __restrict__ ws, float* __restrict__ out) {
  __shared__ f16 S[16 * SSTR];                 // 141,568 B: scores then exp values
  __shared__ float lvl1[23 * 48];              // per-row pooled pyramid scratch
  __shared__ float lvl2[11 * 24];
  __shared__ float lvl3[5 * 12];
  __shared__ float u0s[16], u1s[16], clxs[16], clys[16], rowsum[16];

  const int tid = threadIdx.x;
  const int blk = blockIdx.x;
  const int b = blk / NTILES;
  const int hw0 = (blk - b * NTILES) * 16;
  const float* GS = (const float*)(ws + OFF_GS);

  if (tid < 16) {   // rank-2 pos-bias row vectors + lookup centers
    int hw = hw0 + tid;
    float cy = coords1[(b * 2 + 1) * NHW + hw];
    float cx = coords1[(b * 2 + 0) * NHW + hw];
    u0s[tid] = cy * GS[0] + cx * GS[2];
    u1s[tid] = cy * GS[1] + cx * GS[3];
    clxs[tid] = clup[(b * 2 + 0) * NHW + hw];
    clys[tid] = clup[(b * 2 + 1) * NHW + hw];
  }
  // A fragments: q_s rows hw0..hw0+15, whole K=256, held in registers (32 VGPR)
  const f16* qb = (const f16*)(ws + OFF_Q);
  const f16* kb = (const f16*)(ws + OFF_K);
  const int lane = tid & 63;
  const int arow = lane & 15, akq = (lane >> 4) * 8;
  f16x8 afrag[8];
#pragma unroll
  for (int ks = 0; ks < 8; ++ks)
    afrag[ks] = *(const f16x8*)&qb[(size_t)(b * NHW + hw0 + arow) * ND + ks * 32 + akq];
  __syncthreads();

  // --- Phase B: S[16][4416] = q_s·kᵀ + pos_bias, stored f16 in LDS ---
  const int wave = tid >> 6;
  for (int nt = wave; nt < NTILES; nt += 8) {
    int j0 = nt * 16;
    const f16* kp = &kb[(size_t)(b * NHW + j0 + arow) * ND + akq];
    f16x8 bfrag[8];
#pragma unroll
    for (int ks = 0; ks < 8; ++ks) bfrag[ks] = *(const f16x8*)&kp[ks * 32];
    f32x4 acc0 = {}, acc1 = {};
#pragma unroll
    for (int ks = 0; ks < 8; ks += 2) {
      acc0 = __builtin_amdgcn_mfma_f32_16x16x32_f16(afrag[ks], bfrag[ks], acc0, 0, 0, 0);
      acc1 = __builtin_amdgcn_mfma_f32_16x16x32_f16(afrag[ks + 1], bfrag[ks + 1], acc1, 0, 0, 0);
    }
    int j = j0 + (lane & 15);
    int yj = j / NW;
    float yf = (float)yj, xf = (float)(j - yj * NW);
    int i0 = (lane >> 4) * 4;
#pragma unroll
    for (int r = 0; r < 4; ++r) {
      float s = acc0[r] + acc1[r] + u0s[i0 + r] * yf + u1s[i0 + r] * xf;
      S[(i0 + r) * SSTR + j] = (f16)s;
    }
  }
  __syncthreads();

  // --- Phase C: per-row softmax (row = tid>>5, 32 lanes/row, wave-synchronous) ---
  {
    const int row = tid >> 5, lh = tid & 31;
    f16* Sr = &S[row * SSTR];
    float m = -1e30f;
    for (int j = lh; j < NHW; j += 32) m = fmaxf(m, (float)Sr[j]);
#pragma unroll
    for (int off = 16; off > 0; off >>= 1) m = fmaxf(m, __shfl_xor(m, off));
    float sum = 0.f;
    for (int j = lh; j < NHW; j += 32) {
      float e = exp2f(((float)Sr[j] - m) * 1.44269504f);
      Sr[j] = (f16)e;
      sum += e;
    }
#pragma unroll
    for (int off = 16; off > 0; off >>= 1) sum += __shfl_xor(sum, off);
    if (lh == 0) rowsum[row] = sum;
  }
  __syncthreads();

  // --- Phase D: per row, pool pyramid + 324 bilinear samples ---
  for (int r = 0; r < 16; ++r) {
    const f16* E = &S[r * SSTR];
    for (int c = tid; c < 23 * 48; c += 512) {
      int yy = c / 48, xx = c - yy * 48;
      const f16* p0 = &E[(2 * yy) * NW + 2 * xx];
      lvl1[c] = (float)p0[0] + (float)p0[1] + (float)p0[NW] + (float)p0[NW + 1];
    }
    __syncthreads();
    for (int c = tid; c < 11 * 24; c += 512) {
      int yy = c / 24, xx = c - yy * 24;
      lvl2[c] = lvl1[(2 * yy) * 48 + 2 * xx] + lvl1[(2 * yy) * 48 + 2 * xx + 1] +
                lvl1[(2 * yy + 1) * 48 + 2 * xx] + lvl1[(2 * yy + 1) * 48 + 2 * xx + 1];
    }
    __syncthreads();
    if (tid < 60) {
      int yy = tid / 12, xx = tid - yy * 12;
      lvl3[tid] = lvl2[(2 * yy) * 24 + 2 * xx] + lvl2[(2 * yy) * 24 + 2 * xx + 1] +
                  lvl2[(2 * yy + 1) * 24 + 2 * xx] + lvl2[(2 * yy + 1) * 24 + 2 * xx + 1];
    }
    __syncthreads();
    if (tid < 324) {
      int lvl = tid / 81, rem = tid - lvl * 81;
      int k0 = rem / 9, k1 = rem - k0 * 9;
      const float wdiv[4] = {1.f, 0.25f, 0.0625f, 0.015625f};
      const int Wi[4] = {96, 48, 24, 12}, Hi[4] = {46, 23, 11, 5};
      // reference quirk: x pairs with d[k0], y with d[k1]
      float xq = clxs[r] / (float)(1 << lvl) + (float)(k0 - 4);
      float yq = clys[r] / (float)(1 << lvl) + (float)(k1 - 4);
      float x0f = floorf(xq), y0f = floorf(yq);
      int x0 = (int)x0f, y0 = (int)y0f;
      float wx1 = xq - x0f, wx0 = 1.f - wx1;
      float wy1 = yq - y0f, wy0 = 1.f - wy1;
      int Wl = Wi[lvl], Hl = Hi[lvl];
      float v = 0.f;
#pragma unroll
      for (int dy = 0; dy < 2; ++dy)
#pragma unroll
        for (int dx = 0; dx < 2; ++dx) {
          int xi = x0 + dx, yi = y0 + dy;
          if (xi >= 0 && xi < Wl && yi >= 0 && yi < Hl) {
            float pv;
            if (lvl == 0)      pv = (float)E[yi * NW + xi];
            else if (lvl == 1) pv = lvl1[yi * 48 + xi];
            else if (lvl == 2) pv = lvl2[yi * 24 + xi];
            else               pv = lvl3[yi * 12 + xi];
            v += pv * (dx ? wx1 : wx0) * (dy ? wy1 : wy0);
          }
        }
      int hw = hw0 + r;
      int h = hw / NW, w = hw - h * NW;
      int ch = lvl * 81 + k0 * 9 + k1;
      out[((size_t)(b * 324 + ch) * NH + h) * NW + w] = v * wdiv[lvl] / rowsum[r];
    }
    __syncthreads();
  }
}

extern "C" void kernel_launch(void* const* d_in, const int* in_sizes, int n_in,
                              void* d_out, int out_size, void* d_ws, size_t ws_size,
                              hipStream_t stream) {
  const float* fmap1 = (const float*)d_in[0];
  const float* fmap2 = (const float*)d_in[1];
  const float* coords1 = (const float*)d_in[2];
  const float* clup = (const float*)d_in[3];
  const float* Wf = (const float*)d_in[4];
  const float* bf = (const float*)d_in[5];
  const float* Wpos = (const float*)d_in[6];
  const float* Wq = (const float*)d_in[7];
  const float* Wk = (const float*)d_in[8];
  char* ws = (char*)d_ws;
  float* out = (float*)d_out;

  prep_kernel<<<dim3(258), dim3(256), 0, stream>>>(Wf, bf, Wpos, Wq, Wk, ws);
  qk_gemm<<<dim3(138, 4, 2), dim3(256), 0, stream>>>(fmap1, fmap2, coords1, ws);
  attn_lookup<<<dim3(NB * NTILES), dim3(512), 0, stream>>>(coords1, clup, ws, out);
}

// Round 2
// 293.804 us; speedup vs baseline: 1.1859x; 1.1859x over previous
//
#include <hip/hip_runtime.h>
#include <cstdint>

typedef _Float16 f16;
typedef __attribute__((ext_vector_type(2))) _Float16 f16x2;
typedef __attribute__((ext_vector_type(4))) _Float16 f16x4;
typedef __attribute__((ext_vector_type(8))) _Float16 f16x8;
typedef __attribute__((ext_vector_type(4))) float f32x4;

#define NB 2
#define NH 46
#define NW 96
#define NHW 4416
#define ND 256
#define NTILES 276   // NHW / 16
#define SSTR 4424    // 4416 + 8 pad

// ---- workspace byte offsets ----
#define OFF_WFQ 0          // (Wf@Wq)/16  f16 [256][256]
#define OFF_WFK 131072     // Wf@Wk       f16 [256][256]
#define OFF_PQ  262144     // (Wpos@Wq)/16 f32 [2][256]
#define OFF_PK  264192     // Wpos@Wk      f32 [2][256]
#define OFF_BQ  266240     // (bf@Wq)/16   f32 [256]
#define OFF_BK  267264     // bf@Wk        f32 [256]
#define OFF_GS  268288     // (Wpos@Wposᵀ)/16 f32 [2][2]
#define OFF_Q   268544     // q/16 f16 [8832][256]
#define OFF_K   4790528    // k    f16 [8832][256]

// ============ K0: tiny weight-product precompute ============
__global__ __launch_bounds__(256) void prep_kernel(
    const float* __restrict__ Wf, const float* __restrict__ bf,
    const float* __restrict__ Wpos, const float* __restrict__ Wq,
    const float* __restrict__ Wk, char* __restrict__ ws) {
  f16* WFQ = (f16*)(ws + OFF_WFQ);
  f16* WFK = (f16*)(ws + OFF_WFK);
  float* PQ = (float*)(ws + OFF_PQ);
  float* PK = (float*)(ws + OFF_PK);
  float* BQ = (float*)(ws + OFF_BQ);
  float* BK = (float*)(ws + OFF_BK);
  float* GS = (float*)(ws + OFF_GS);
  int bid = blockIdx.x, d = threadIdx.x;
  if (bid < 256) {           // row c of Wf@Wq and Wf@Wk
    int c = bid;
    float aq = 0.f, ak = 0.f;
    for (int t = 0; t < 256; ++t) {
      float wf = Wf[c * 256 + t];
      aq += wf * Wq[t * 256 + d];
      ak += wf * Wk[t * 256 + d];
    }
    WFQ[c * 256 + d] = (f16)(aq * 0.0625f);
    WFK[c * 256 + d] = (f16)ak;
  } else if (bid == 256) {   // Wpos@Wq, Wpos@Wk, bf@Wq, bf@Wk
    float pq0 = 0, pq1 = 0, pk0 = 0, pk1 = 0, bq = 0, bk = 0;
    for (int c = 0; c < 256; ++c) {
      float wq = Wq[c * 256 + d], wk = Wk[c * 256 + d];
      pq0 += Wpos[c] * wq;       pq1 += Wpos[256 + c] * wq;
      pk0 += Wpos[c] * wk;       pk1 += Wpos[256 + c] * wk;
      bq  += bf[c] * wq;         bk  += bf[c] * wk;
    }
    PQ[d] = pq0 * 0.0625f; PQ[256 + d] = pq1 * 0.0625f;
    PK[d] = pk0;           PK[256 + d] = pk1;
    BQ[d] = bq * 0.0625f;  BK[d] = bk;
  } else if (d < 4) {        // G = Wpos@Wposᵀ / 16
    int a = d >> 1, b2 = d & 1;
    float g = 0;
    for (int t = 0; t < 256; ++t) g += Wpos[a * 256 + t] * Wpos[b2 * 256 + t];
    GS[d] = g * 0.0625f;
  }
}

// ============ K1: q_s/k = fmapᵀ @ Wfx + rank-2 pos + bias (fused transpose) ============
__global__ __launch_bounds__(256) void qk_gemm(
    const float* __restrict__ fmap1, const float* __restrict__ fmap2,
    const float* __restrict__ coords1, char* __restrict__ ws) {
  __shared__ f16 As[64 * 40];
  __shared__ f16 Bs[64 * 40];
  __shared__ float py[64], px[64];
  const int z = blockIdx.z;
  const float* fmap = z ? fmap2 : fmap1;
  const f16* Wt = (const f16*)(ws + (z ? OFF_WFK : OFF_WFQ));
  const float* P = (const float*)(ws + (z ? OFF_PK : OFF_PQ));
  const float* bias = (const float*)(ws + (z ? OFF_BK : OFF_BQ));
  f16* outb = (f16*)(ws + (z ? OFF_K : OFF_Q));
  const int t = threadIdx.x;
  const int g0 = blockIdx.x * 64;
  const int b = g0 / NHW;
  const int hwb = g0 - b * NHW;
  const int d0 = blockIdx.y * 64;
  if (t < 64) {
    int hw = hwb + t;
    if (z == 0) {
      py[t] = coords1[(b * 2 + 1) * NHW + hw];
      px[t] = coords1[(b * 2 + 0) * NHW + hw];
    } else {
      int y = hw / NW;
      py[t] = (float)y;
      px[t] = (float)(hw - y * NW);
    }
  }
  const int lane = t & 63, wave = t >> 6;
  const int wr = (wave >> 1) * 32, wc = (wave & 1) * 32;
  const int hwl = t & 63, cl0 = t >> 6;
  f32x4 acc[2][2] = {};
  for (int kt = 0; kt < 8; ++kt) {
    int kk = kt * 32;
    __syncthreads();
#pragma unroll
    for (int i = 0; i < 8; ++i) {
      int c = cl0 + i * 4;
      As[hwl * 40 + c] = (f16)fmap[(size_t)(b * ND + kk + c) * NHW + hwb + hwl];
      Bs[hwl * 40 + c] = Wt[(kk + c) * ND + d0 + hwl];
    }
    __syncthreads();
    int row = lane & 15, kq = (lane >> 4) * 8;
    f16x8 a0 = *(const f16x8*)&As[(wr + row) * 40 + kq];
    f16x8 a1 = *(const f16x8*)&As[(wr + 16 + row) * 40 + kq];
    f16x8 b0 = *(const f16x8*)&Bs[(wc + row) * 40 + kq];
    f16x8 b1 = *(const f16x8*)&Bs[(wc + 16 + row) * 40 + kq];
    acc[0][0] = __builtin_amdgcn_mfma_f32_16x16x32_f16(a0, b0, acc[0][0], 0, 0, 0);
    acc[0][1] = __builtin_amdgcn_mfma_f32_16x16x32_f16(a0, b1, acc[0][1], 0, 0, 0);
    acc[1][0] = __builtin_amdgcn_mfma_f32_16x16x32_f16(a1, b0, acc[1][0], 0, 0, 0);
    acc[1][1] = __builtin_amdgcn_mfma_f32_16x16x32_f16(a1, b1, acc[1][1], 0, 0, 0);
  }
#pragma unroll
  for (int fi = 0; fi < 2; ++fi)
#pragma unroll
    for (int fj = 0; fj < 2; ++fj)
#pragma unroll
      for (int r = 0; r < 4; ++r) {
        int rowl = wr + fi * 16 + (lane >> 4) * 4 + r;
        int d = d0 + wc + fj * 16 + (lane & 15);
        float v = acc[fi][fj][r] + bias[d] + py[rowl] * P[d] + px[rowl] * P[ND + d];
        outb[(size_t)(g0 + rowl) * ND + d] = (f16)v;
      }
}

// ============ K2: fused scores-GEMM + softmax + pyramid + 4-level lookup ============
// 552 blocks, 1024 threads (16 waves), ~148 KB LDS, 1 block/CU.
// XCD-batch partition: blk%8 -> XCD; XCDs 0-3 serve batch 0, 4-7 batch 1,
// so each XCD's L2 holds only ONE batch's K (2.26 MB < 4 MB) -> L2-resident.
__global__ __launch_bounds__(1024) void attn_lookup(
    const float* __restrict__ coords1, const float* __restrict__ clup,
    const char* __restrict__ ws, float* __restrict__ out) {
  __shared__ f16 S[16 * SSTR];                 // 141,568 B: scores then exp values
  __shared__ f16 lv1[2][23 * 48];              // row-pair pooled pyramid (f16)
  __shared__ f16 lv2[2][11 * 24];
  __shared__ f16 lv3[2][5 * 12];
  __shared__ float u0s[16], u1s[16], clxs[16], clys[16], rinv[16];

  const int tid = threadIdx.x;
  // --- XCD-aware block -> (batch, tile) mapping (bijective over 552) ---
  const int blk0 = blockIdx.x;
  const int xcd = blk0 & 7;
  const int b = xcd >> 2;                          // batch from XCD half
  const int hw0 = ((blk0 >> 3) * 4 + (xcd & 3)) * 16;
  const float* GS = (const float*)(ws + OFF_GS);

  if (tid < 16) {
    int hw = hw0 + tid;
    float cy = coords1[(b * 2 + 1) * NHW + hw];
    float cx = coords1[(b * 2 + 0) * NHW + hw];
    u0s[tid] = cy * GS[0] + cx * GS[2];
    u1s[tid] = cy * GS[1] + cx * GS[3];
    clxs[tid] = clup[(b * 2 + 0) * NHW + hw];
    clys[tid] = clup[(b * 2 + 1) * NHW + hw];
  }
  const f16* qb = (const f16*)(ws + OFF_Q);
  const f16* kb = (const f16*)(ws + OFF_K);
  const int lane = tid & 63;
  const int arow = lane & 15, akq = (lane >> 4) * 8;
  f16x8 afrag[8];
#pragma unroll
  for (int ks = 0; ks < 8; ++ks)
    afrag[ks] = *(const f16x8*)&qb[(size_t)(b * NHW + hw0 + arow) * ND + ks * 32 + akq];
  __syncthreads();

  // --- Phase B: S[16][4416] = q_s·kᵀ + pos_bias, f16 in LDS (16 waves) ---
  const int wave = tid >> 6;
  for (int nt = wave; nt < NTILES; nt += 16) {
    int j0 = nt * 16;
    const f16* kp = &kb[(size_t)(b * NHW + j0 + arow) * ND + akq];
    f16x8 bfrag[8];
#pragma unroll
    for (int ks = 0; ks < 8; ++ks) bfrag[ks] = *(const f16x8*)&kp[ks * 32];
    f32x4 acc0 = {}, acc1 = {};
#pragma unroll
    for (int ks = 0; ks < 8; ks += 2) {
      acc0 = __builtin_amdgcn_mfma_f32_16x16x32_f16(afrag[ks], bfrag[ks], acc0, 0, 0, 0);
      acc1 = __builtin_amdgcn_mfma_f32_16x16x32_f16(afrag[ks + 1], bfrag[ks + 1], acc1, 0, 0, 0);
    }
    int j = j0 + (lane & 15);
    int yj = j / NW;
    float yf = (float)yj, xf = (float)(j - yj * NW);
    int i0 = (lane >> 4) * 4;
#pragma unroll
    for (int r = 0; r < 4; ++r) {
      float s = acc0[r] + acc1[r] + u0s[i0 + r] * yf + u1s[i0 + r] * xf;
      S[(i0 + r) * SSTR + j] = (f16)s;
    }
  }
  __syncthreads();

  // --- Phase C: per-row softmax, one wave (64 lanes) per row, f16x4 loads ---
  {
    const int row = tid >> 6, lh = lane;     // wave w -> row w
    f16* Sr = &S[row * SSTR];
    float m = -1e30f;
    for (int q = lh; q < 1104; q += 64) {    // 1104 quads = 4416
      f16x4 v = *(const f16x4*)&Sr[q * 4];
      m = fmaxf(m, fmaxf(fmaxf((float)v[0], (float)v[1]),
                         fmaxf((float)v[2], (float)v[3])));
    }
#pragma unroll
    for (int off = 32; off > 0; off >>= 1) m = fmaxf(m, __shfl_xor(m, off));
    float sum = 0.f;
    for (int q = lh; q < 1104; q += 64) {
      f16x4 v = *(const f16x4*)&Sr[q * 4];
      float e0 = exp2f(((float)v[0] - m) * 1.44269504f);
      float e1 = exp2f(((float)v[1] - m) * 1.44269504f);
      float e2 = exp2f(((float)v[2] - m) * 1.44269504f);
      float e3 = exp2f(((float)v[3] - m) * 1.44269504f);
      f16x4 w; w[0] = (f16)e0; w[1] = (f16)e1; w[2] = (f16)e2; w[3] = (f16)e3;
      *(f16x4*)&Sr[q * 4] = w;
      sum += (e0 + e1) + (e2 + e3);
    }
#pragma unroll
    for (int off = 32; off > 0; off >>= 1) sum += __shfl_xor(sum, off);
    if (lh == 0) rinv[row] = 1.f / sum;
  }
  __syncthreads();

  // --- Phase D: row PAIRS in parallel (512 threads each), f16x2 pool reads ---
  const int half = tid >> 9;                 // 0 or 1: which row of the pair
  const int ts = tid & 511;
  f16* L1 = lv1[half];
  f16* L2 = lv2[half];
  f16* L3 = lv3[half];
  for (int p = 0; p < 8; ++p) {
    const int r = p * 2 + half;
    const f16* E = &S[r * SSTR];
    for (int c = ts; c < 23 * 48; c += 512) {
      int yy = c / 48, xx = c - yy * 48;
      f16x2 a = *(const f16x2*)&E[(2 * yy) * NW + 2 * xx];
      f16x2 bb = *(const f16x2*)&E[(2 * yy + 1) * NW + 2 * xx];
      L1[c] = (f16)(((float)a[0] + (float)a[1]) + ((float)bb[0] + (float)bb[1]));
    }
    __syncthreads();
    if (ts < 11 * 24) {
      int yy = ts / 24, xx = ts - yy * 24;
      f16x2 a = *(const f16x2*)&L1[(2 * yy) * 48 + 2 * xx];
      f16x2 bb = *(const f16x2*)&L1[(2 * yy + 1) * 48 + 2 * xx];
      L2[ts] = (f16)(((float)a[0] + (float)a[1]) + ((float)bb[0] + (float)bb[1]));
    }
    __syncthreads();
    if (ts < 5 * 12) {
      int yy = ts / 12, xx = ts - yy * 12;
      f16x2 a = *(const f16x2*)&L2[(2 * yy) * 24 + 2 * xx];
      f16x2 bb = *(const f16x2*)&L2[(2 * yy + 1) * 24 + 2 * xx];
      L3[ts] = (f16)(((float)a[0] + (float)a[1]) + ((float)bb[0] + (float)bb[1]));
    }
    __syncthreads();
    if (ts < 324) {
      int lvl = ts / 81, rem = ts - lvl * 81;
      int k0 = rem / 9, k1 = rem - k0 * 9;
      const float wdiv[4] = {1.f, 0.25f, 0.0625f, 0.015625f};
      const int Wi[4] = {96, 48, 24, 12}, Hi[4] = {46, 23, 11, 5};
      // reference quirk: x pairs with d[k0], y with d[k1]
      float xq = clxs[r] / (float)(1 << lvl) + (float)(k0 - 4);
      float yq = clys[r] / (float)(1 << lvl) + (float)(k1 - 4);
      float x0f = floorf(xq), y0f = floorf(yq);
      int x0 = (int)x0f, y0 = (int)y0f;
      float wx1 = xq - x0f, wx0 = 1.f - wx1;
      float wy1 = yq - y0f, wy0 = 1.f - wy1;
      int Wl = Wi[lvl], Hl = Hi[lvl];
      float v = 0.f;
#pragma unroll
      for (int dy = 0; dy < 2; ++dy)
#pragma unroll
        for (int dx = 0; dx < 2; ++dx) {
          int xi = x0 + dx, yi = y0 + dy;
          if (xi >= 0 && xi < Wl && yi >= 0 && yi < Hl) {
            float pv;
            if (lvl == 0)      pv = (float)E[yi * NW + xi];
            else if (lvl == 1) pv = (float)L1[yi * 48 + xi];
            else if (lvl == 2) pv = (float)L2[yi * 24 + xi];
            else               pv = (float)L3[yi * 12 + xi];
            v += pv * (dx ? wx1 : wx0) * (dy ? wy1 : wy0);
          }
        }
      int hw = hw0 + r;
      int h = hw / NW, w = hw - h * NW;
      int ch = lvl * 81 + k0 * 9 + k1;
      out[((size_t)(b * 324 + ch) * NH + h) * NW + w] = v * wdiv[lvl] * rinv[r];
    }
    __syncthreads();
  }
}

extern "C" void kernel_launch(void* const* d_in, const int* in_sizes, int n_in,
                              void* d_out, int out_size, void* d_ws, size_t ws_size,
                              hipStream_t stream) {
  const float* fmap1 = (const float*)d_in[0];
  const float* fmap2 = (const float*)d_in[1];
  const float* coords1 = (const float*)d_in[2];
  const float* clup = (const float*)d_in[3];
  const float* Wf = (const float*)d_in[4];
  const float* bf = (const float*)d_in[5];
  const float* Wpos = (const float*)d_in[6];
  const float* Wq = (const float*)d_in[7];
  const float* Wk = (const float*)d_in[8];
  char* ws = (char*)d_ws;
  float* out = (float*)d_out;

  prep_kernel<<<dim3(258), dim3(256), 0, stream>>>(Wf, bf, Wpos, Wq, Wk, ws);
  qk_gemm<<<dim3(138, 4, 2), dim3(256), 0, stream>>>(fmap1, fmap2, coords1, ws);
  attn_lookup<<<dim3(NB * NTILES), dim3(1024), 0, stream>>>(coords1, clup, ws, out);
}